// Round 1
// baseline (1522.485 us; speedup 1.0000x reference)
//
#include <hip/hip_runtime.h>

#define M_DIM 8192
#define K_DIM 4096
#define N_DIM 16384

typedef unsigned short u16;
typedef __attribute__((ext_vector_type(8))) unsigned short ushort8;
typedef __attribute__((ext_vector_type(8))) short short8;
typedef __attribute__((ext_vector_type(4))) float f32x4;

// fp32 -> bf16 round-to-nearest-even (bit trick; inputs are finite here)
__device__ __forceinline__ u16 f2b(float f) {
  union { float f; unsigned u; } v; v.f = f;
  unsigned r = (v.u + 0x7fffu + ((v.u >> 16) & 1u)) >> 16;
  return (u16)r;
}

// ---- pre-pass 1: x fp32 -> bf16 ------------------------------------------
__global__ void cvt_x_kernel(const float* __restrict__ x, u16* __restrict__ xb, int n8) {
  int i = blockIdx.x * blockDim.x + threadIdx.x;
  const int stride = gridDim.x * blockDim.x;
  const float4* xf = reinterpret_cast<const float4*>(x);
  ushort8* o = reinterpret_cast<ushort8*>(xb);
  for (; i < n8; i += stride) {
    float4 a = xf[2 * i], b = xf[2 * i + 1];
    ushort8 r;
    r[0] = f2b(a.x); r[1] = f2b(a.y); r[2] = f2b(a.z); r[3] = f2b(a.w);
    r[4] = f2b(b.x); r[5] = f2b(b.y); r[6] = f2b(b.z); r[7] = f2b(b.w);
    o[i] = r;
  }
}

// ---- pre-pass 2: w_q int32 * block scale -> bf16 -------------------------
__global__ void dequant_w_kernel(const int* __restrict__ wq, const float* __restrict__ wsc,
                                 u16* __restrict__ wb, int n8) {
  int i = blockIdx.x * blockDim.x + threadIdx.x;
  const int stride = gridDim.x * blockDim.x;
  const int4* q = reinterpret_cast<const int4*>(wq);
  ushort8* o = reinterpret_cast<ushort8*>(wb);
  for (; i < n8; i += stride) {
    int n = i >> 9;            // i / (K/8): 512 groups of 8 per row
    int k8 = i & 511;
    float s = wsc[(n >> 7) * (K_DIM / 128) + (k8 >> 4)];  // k8*8/128 == k8/16
    int4 a = q[2 * i], b = q[2 * i + 1];
    ushort8 r;
    r[0] = f2b((float)a.x * s); r[1] = f2b((float)a.y * s);
    r[2] = f2b((float)a.z * s); r[3] = f2b((float)a.w * s);
    r[4] = f2b((float)b.x * s); r[5] = f2b((float)b.y * s);
    r[6] = f2b((float)b.z * s); r[7] = f2b((float)b.w * s);
    o[i] = r;
  }
}

// ---- async global -> LDS, 16 B per lane ----------------------------------
__device__ __forceinline__ void gload16(const void* g, void* l) {
  __builtin_amdgcn_global_load_lds(
      (const __attribute__((address_space(1))) unsigned int*)g,
      (__attribute__((address_space(3))) unsigned int*)l, 16, 0, 0);
}

// ---- GEMM: C = A(bf16)[M,K] * B(bf16)[N,K]^T + bias ----------------------
// 128x128 tile, BK=32, 4 waves (2x2), each wave a 64x64 sub-tile (4x4 frags)
__global__ __launch_bounds__(256) void gemm_kernel(
    const u16* __restrict__ A, const u16* __restrict__ B,
    const float* __restrict__ bias, float* __restrict__ C) {
  __shared__ u16 As[128 * 32];
  __shared__ u16 Bs[128 * 32];

  const int tid = threadIdx.x;
  const int lane = tid & 63;
  const int wid = tid >> 6;
  const int wr = wid >> 1;
  const int wc = wid & 1;

  // XCD-aware bijective swizzle (nwg = 8192, divisible by 8)
  const int bid = blockIdx.x;
  const int cpx = gridDim.x >> 3;
  const int swz = (bid & 7) * cpx + (bid >> 3);
  const int NT = N_DIM / 128;       // 128
  const int tm = swz / NT;
  const int tn = swz - tm * NT;

  // staging addresses: instr j covers LDS elements [j*2048 + tid*8 .. +8)
  //  -> row = tid/4 + j*64, col = (tid%4)*8 of the [128][32] tile
  const int row_a = tid >> 2;
  const int col8 = (tid & 3) << 3;
  const u16* gA = A + (size_t)(tm * 128 + row_a) * K_DIM + col8;
  const u16* gB = B + (size_t)(tn * 128 + row_a) * K_DIM + col8;
  char* lA = (char*)As + ((tid >> 6) << 10);  // wave-uniform LDS base
  char* lB = (char*)Bs + ((tid >> 6) << 10);

  f32x4 acc[4][4] = {};

  const int ar = wr * 64 + (lane & 15);
  const int br = wc * 64 + (lane & 15);
  const int kc = (lane >> 4) << 3;

  for (int k0 = 0; k0 < K_DIM; k0 += 32) {
    gload16(gA + k0, lA);
    gload16(gA + k0 + (size_t)64 * K_DIM, lA + 4096);
    gload16(gB + k0, lB);
    gload16(gB + k0 + (size_t)64 * K_DIM, lB + 4096);
    __syncthreads();   // drains vmcnt: staged tile visible to all waves

    short8 af[4], bf[4];
#pragma unroll
    for (int mi = 0; mi < 4; ++mi)
      af[mi] = *(const short8*)(&As[(ar + mi * 16) * 32 + kc]);
#pragma unroll
    for (int ni = 0; ni < 4; ++ni)
      bf[ni] = *(const short8*)(&Bs[(br + ni * 16) * 32 + kc]);
#pragma unroll
    for (int mi = 0; mi < 4; ++mi)
#pragma unroll
      for (int ni = 0; ni < 4; ++ni)
        acc[mi][ni] = __builtin_amdgcn_mfma_f32_16x16x32_bf16(
            af[mi], bf[ni], acc[mi][ni], 0, 0, 0);
    __syncthreads();   // all waves done reading before next overwrite
  }

  // epilogue: C/D layout col=lane&15, row=(lane>>4)*4+reg (m89-verified)
  const int crow = tm * 128 + wr * 64 + ((lane >> 4) << 2);
  const int ccol = tn * 128 + wc * 64 + (lane & 15);
#pragma unroll
  for (int ni = 0; ni < 4; ++ni) {
    float bv = bias[ccol + ni * 16];
#pragma unroll
    for (int mi = 0; mi < 4; ++mi) {
#pragma unroll
      for (int r = 0; r < 4; ++r) {
        C[(size_t)(crow + mi * 16 + r) * N_DIM + (ccol + ni * 16)] =
            acc[mi][ni][r] + bv;
      }
    }
  }
}

extern "C" void kernel_launch(void* const* d_in, const int* in_sizes, int n_in,
                              void* d_out, int out_size, void* d_ws, size_t ws_size,
                              hipStream_t stream) {
  const float* x    = (const float*)d_in[0];
  const int*   wq   = (const int*)d_in[1];
  const float* wsc  = (const float*)d_in[2];
  const float* bias = (const float*)d_in[3];
  float* out = (float*)d_out;

  const size_t xb_bytes = (size_t)M_DIM * K_DIM * 2;  // 64 MB
  const size_t wb_bytes = (size_t)N_DIM * K_DIM * 2;  // 128 MB
  if (ws_size < xb_bytes + wb_bytes) return;          // need 192 MB scratch

  u16* xb = (u16*)d_ws;
  u16* wb = (u16*)((char*)d_ws + xb_bytes);

  cvt_x_kernel<<<2048, 256, 0, stream>>>(x, xb, M_DIM * K_DIM / 8);
  dequant_w_kernel<<<2048, 256, 0, stream>>>(wq, wsc, wb, N_DIM * K_DIM / 8);
  gemm_kernel<<<(M_DIM / 128) * (N_DIM / 128), 256, 0, stream>>>(xb, wb, bias, out);
}

// Round 2
// 1147.404 us; speedup vs baseline: 1.3269x; 1.3269x over previous
//
#include <hip/hip_runtime.h>

#define M_DIM 8192
#define K_DIM 4096
#define N_DIM 16384
#define KT 64   // K_DIM / 64 K-tiles

typedef unsigned short u16;
typedef __attribute__((ext_vector_type(8))) unsigned short ushort8;
typedef __attribute__((ext_vector_type(8))) short short8;
typedef __attribute__((ext_vector_type(4))) float f32x4;

// fp32 -> bf16 round-to-nearest-even
__device__ __forceinline__ u16 f2b(float f) {
  union { float f; unsigned u; } v; v.f = f;
  unsigned r = (v.u + 0x7fffu + ((v.u >> 16) & 1u)) >> 16;
  return (u16)r;
}

// ---- pre-pass 1: x fp32 -> bf16 ------------------------------------------
__global__ void cvt_x_kernel(const float* __restrict__ x, u16* __restrict__ xb, int n8) {
  int i = blockIdx.x * blockDim.x + threadIdx.x;
  const int stride = gridDim.x * blockDim.x;
  const float4* xf = reinterpret_cast<const float4*>(x);
  ushort8* o = reinterpret_cast<ushort8*>(xb);
  for (; i < n8; i += stride) {
    float4 a = xf[2 * i], b = xf[2 * i + 1];
    ushort8 r;
    r[0] = f2b(a.x); r[1] = f2b(a.y); r[2] = f2b(a.z); r[3] = f2b(a.w);
    r[4] = f2b(b.x); r[5] = f2b(b.y); r[6] = f2b(b.z); r[7] = f2b(b.w);
    o[i] = r;
  }
}

// ---- pre-pass 2: w_q int32 * block scale -> bf16 -------------------------
__global__ void dequant_w_kernel(const int* __restrict__ wq, const float* __restrict__ wsc,
                                 u16* __restrict__ wb, int n8) {
  int i = blockIdx.x * blockDim.x + threadIdx.x;
  const int stride = gridDim.x * blockDim.x;
  const int4* q = reinterpret_cast<const int4*>(wq);
  ushort8* o = reinterpret_cast<ushort8*>(wb);
  for (; i < n8; i += stride) {
    int n = i >> 9;
    int k8 = i & 511;
    float s = wsc[(n >> 7) * (K_DIM / 128) + (k8 >> 4)];
    int4 a = q[2 * i], b = q[2 * i + 1];
    ushort8 r;
    r[0] = f2b((float)a.x * s); r[1] = f2b((float)a.y * s);
    r[2] = f2b((float)a.z * s); r[3] = f2b((float)a.w * s);
    r[4] = f2b((float)b.x * s); r[5] = f2b((float)b.y * s);
    r[6] = f2b((float)b.z * s); r[7] = f2b((float)b.w * s);
    o[i] = r;
  }
}

// ---- async global -> LDS, 16 B per lane (dest = wave base + lane*16) -----
__device__ __forceinline__ void gload16(const void* g, void* l) {
  __builtin_amdgcn_global_load_lds(
      (const __attribute__((address_space(1))) unsigned int*)g,
      (__attribute__((address_space(3))) unsigned int*)l, 16, 0, 0);
}

#define BAR() do { asm volatile("" ::: "memory"); \
                   __builtin_amdgcn_s_barrier();  \
                   asm volatile("" ::: "memory"); } while (0)

#define MF(a, b, c) __builtin_amdgcn_mfma_f32_16x16x32_bf16(a, b, c, 0, 0, 0)

// ---- 256x256x64 8-wave 8-phase GEMM: C = A[M,K] * B[N,K]^T + bias --------
__global__ __launch_bounds__(512, 2) void gemm_kernel(
    const u16* __restrict__ A, const u16* __restrict__ B,
    const float* __restrict__ bias, float* __restrict__ C) {
  // buf p (p=0,1): A tile at p*65536 (256 rows x 64 k, 128B/row),
  //                B tile at p*65536+32768. Total 128 KiB.
  __shared__ __align__(128) char lds[131072];

  const int tid = threadIdx.x;
  const int lane = tid & 63, wid = tid >> 6;
  const int wr = wid >> 2, wc = wid & 3;    // 2 x 4 wave grid

  // XCD-bijective swizzle: 2048 blocks, 8 XCDs, 256 per XCD
  const int bid = blockIdx.x;
  const int swz = (bid & 7) * 256 + (bid >> 3);
  const int tm = swz >> 6, tn = swz & 63;   // 32 x 64 tiles

  // ---- staging: per-lane pre-swizzled global source, linear LDS dest ----
  // stage call covers 64 rows: row = wid*8 + lane/8, 16B unit u' = lane&7
  // stored logical k-unit u = u' ^ (row&7)  (involution)
  const int srow = (wid << 3) + (lane >> 3);
  const int kswz = ((lane & 7) ^ ((lane >> 3) & 7)) << 3;  // element offset
  const u16* aSrc = A + (size_t)(tm * 256 + srow) * K_DIM + kswz;
  const u16* bSrc = B + (size_t)(tn * 256 + srow) * K_DIM + kswz;
  const int ldst = wid << 10;

#define STAGE_A(tt, h, s, b) gload16(aSrc + (size_t)((h)*128 + (s)*64) * K_DIM + (size_t)(tt)*64, \
                                     lds + (b)*65536 + (h)*16384 + (s)*8192 + ldst)
#define STAGE_B(tt, h, s, b) gload16(bSrc + (size_t)((h)*128 + (s)*64) * K_DIM + (size_t)(tt)*64, \
                                     lds + (b)*65536 + 32768 + (h)*16384 + (s)*8192 + ldst)

  // ---- fragment read addressing (swizzled): row&7 == lane&7 always ------
  const int hi = lane >> 4, lo3 = lane & 7;
  const int ak0 = ((0 + hi) ^ lo3) << 4;   // kk=0 unit, 16B units
  const int ak1 = ((4 + hi) ^ lo3) << 4;   // kk=1 unit
  const int aoff = (wr * 128 + (lane & 15)) * 128;
  const int boff = 32768 + (wc * 64 + (lane & 15)) * 128;

  f32x4 acc[8][4] = {};

  // ---- prologue: stage tiles 0 (buf0) and 1 (buf1) ----------------------
  STAGE_A(0, 0, 0, 0); STAGE_A(0, 0, 1, 0); STAGE_A(0, 1, 0, 0); STAGE_A(0, 1, 1, 0);
  STAGE_B(0, 0, 0, 0); STAGE_B(0, 0, 1, 0); STAGE_B(0, 1, 0, 0); STAGE_B(0, 1, 1, 0);
  STAGE_A(1, 0, 0, 1); STAGE_A(1, 0, 1, 1); STAGE_A(1, 1, 0, 1); STAGE_A(1, 1, 1, 1);
  STAGE_B(1, 0, 0, 1); STAGE_B(1, 0, 1, 1); STAGE_B(1, 1, 0, 1); STAGE_B(1, 1, 1, 1);
  asm volatile("s_waitcnt vmcnt(8)" ::: "memory");  // tile 0 landed; tile 1 in flight
  BAR();

#define AFRAGS(q, P) \
  const short8 P##0 = *(const short8*)(Ab + (2*(q)    ) * 2048 + ak0); \
  const short8 P##1 = *(const short8*)(Ab + (2*(q)    ) * 2048 + ak1); \
  const short8 P##2 = *(const short8*)(Ab + (2*(q) + 1) * 2048 + ak0); \
  const short8 P##3 = *(const short8*)(Ab + (2*(q) + 1) * 2048 + ak1);

#define QUAD(q, P) \
  __builtin_amdgcn_s_setprio(1); \
  acc[2*(q)][0]   = MF(P##0, bf00, acc[2*(q)][0]);   acc[2*(q)][0]   = MF(P##1, bf01, acc[2*(q)][0]); \
  acc[2*(q)][1]   = MF(P##0, bf10, acc[2*(q)][1]);   acc[2*(q)][1]   = MF(P##1, bf11, acc[2*(q)][1]); \
  acc[2*(q)][2]   = MF(P##0, bf20, acc[2*(q)][2]);   acc[2*(q)][2]   = MF(P##1, bf21, acc[2*(q)][2]); \
  acc[2*(q)][3]   = MF(P##0, bf30, acc[2*(q)][3]);   acc[2*(q)][3]   = MF(P##1, bf31, acc[2*(q)][3]); \
  acc[2*(q)+1][0] = MF(P##2, bf00, acc[2*(q)+1][0]); acc[2*(q)+1][0] = MF(P##3, bf01, acc[2*(q)+1][0]); \
  acc[2*(q)+1][1] = MF(P##2, bf10, acc[2*(q)+1][1]); acc[2*(q)+1][1] = MF(P##3, bf11, acc[2*(q)+1][1]); \
  acc[2*(q)+1][2] = MF(P##2, bf20, acc[2*(q)+1][2]); acc[2*(q)+1][2] = MF(P##3, bf21, acc[2*(q)+1][2]); \
  acc[2*(q)+1][3] = MF(P##2, bf30, acc[2*(q)+1][3]); acc[2*(q)+1][3] = MF(P##3, bf31, acc[2*(q)+1][3]); \
  __builtin_amdgcn_s_setprio(0);

  for (int t = 0; t < KT; ++t) {
    const int p = t & 1, pn = p ^ 1;
    const char* Ab = lds + p * 65536 + aoff;
    const char* Bb = lds + p * 65536 + boff;

    // ---- phase 0: B frags (8) + A Q0 (4); stage A(t+1) half0 -> buf pn --
    AFRAGS(0, pa)
    const short8 bf00 = *(const short8*)(Bb + 0 * 2048 + ak0);
    const short8 bf01 = *(const short8*)(Bb + 0 * 2048 + ak1);
    const short8 bf10 = *(const short8*)(Bb + 1 * 2048 + ak0);
    const short8 bf11 = *(const short8*)(Bb + 1 * 2048 + ak1);
    const short8 bf20 = *(const short8*)(Bb + 2 * 2048 + ak0);
    const short8 bf21 = *(const short8*)(Bb + 2 * 2048 + ak1);
    const short8 bf30 = *(const short8*)(Bb + 3 * 2048 + ak0);
    const short8 bf31 = *(const short8*)(Bb + 3 * 2048 + ak1);
    if (t > 0 && t + 1 < KT) { STAGE_A(t + 1, 0, 0, pn); STAGE_A(t + 1, 0, 1, pn); }
    BAR();
    QUAD(0, pa)
    BAR();

    // ---- phase 1: A Q1; stage A(t+1) half1 -> buf pn --------------------
    AFRAGS(1, pb)
    if (t > 0 && t + 1 < KT) { STAGE_A(t + 1, 1, 0, pn); STAGE_A(t + 1, 1, 1, pn); }
    BAR();
    QUAD(1, pb)
    BAR();

    // ---- phase 2: A Q2; stage B(t+2) half0 -> buf p (B(p) free since ph0)
    AFRAGS(2, pc)
    if (t + 2 < KT) { STAGE_B(t + 2, 0, 0, p); STAGE_B(t + 2, 0, 1, p); }
    BAR();
    QUAD(2, pc)
    BAR();

    // ---- phase 3: A Q3; stage B(t+2) half1; counted vmcnt ---------------
    AFRAGS(3, pd)
    if (t + 2 < KT) { STAGE_B(t + 2, 1, 0, p); STAGE_B(t + 2, 1, 1, p); }
    if (t < KT - 2)       asm volatile("s_waitcnt vmcnt(4)" ::: "memory");
    else if (t == KT - 2) asm volatile("s_waitcnt vmcnt(0)" ::: "memory");
    BAR();
    QUAD(3, pd)
    BAR();
  }

  // ---- epilogue: C/D layout col=lane&15, row=(lane>>4)*4+reg ------------
  const int crow0 = tm * 256 + wr * 128 + ((lane >> 4) << 2);
  const int ccol0 = tn * 256 + wc * 64 + (lane & 15);
#pragma unroll
  for (int ni = 0; ni < 4; ++ni) {
    const float bv = bias[ccol0 + ni * 16];
#pragma unroll
    for (int mi = 0; mi < 8; ++mi) {
#pragma unroll
      for (int r = 0; r < 4; ++r) {
        C[(size_t)(crow0 + mi * 16 + r) * N_DIM + ccol0 + ni * 16] =
            acc[mi][ni][r] + bv;
      }
    }
  }
}

extern "C" void kernel_launch(void* const* d_in, const int* in_sizes, int n_in,
                              void* d_out, int out_size, void* d_ws, size_t ws_size,
                              hipStream_t stream) {
  const float* x    = (const float*)d_in[0];
  const int*   wq   = (const int*)d_in[1];
  const float* wsc  = (const float*)d_in[2];
  const float* bias = (const float*)d_in[3];
  float* out = (float*)d_out;

  const size_t xb_bytes = (size_t)M_DIM * K_DIM * 2;  // 64 MB
  const size_t wb_bytes = (size_t)N_DIM * K_DIM * 2;  // 128 MB
  if (ws_size < xb_bytes + wb_bytes) return;

  u16* xb = (u16*)d_ws;
  u16* wb = (u16*)((char*)d_ws + xb_bytes);

  cvt_x_kernel<<<2048, 256, 0, stream>>>(x, xb, M_DIM * K_DIM / 8);
  dequant_w_kernel<<<2048, 256, 0, stream>>>(wq, wsc, wb, N_DIM * K_DIM / 8);
  gemm_kernel<<<(M_DIM / 256) * (N_DIM / 256), 512, 0, stream>>>(xb, wb, bias, out);
}